// Round 4
// baseline (308.444 us; speedup 1.0000x reference)
//
#include <hip/hip_runtime.h>

// DirectNormLoss: B=16384 rows, D=2048 features, 1000 classes.
// loss = mean_i [ 1 - <s_i, c_i> / (||c_i|| * max(||s_i||, ||t_i||)) ]
//
// R3: MLP theory falsified (R0-R2 all ~1.8 TB/s HBM / 3.6 TB/s logical
// regardless of structure). New theory: LLC/fabric read BW is the wall;
// cut logical traffic by class-grouping rows (counting sort) so each wave
// holds its class center in REGISTERS (32 floats/lane) and streams only
// s/t in the inner loop. T_EMB logical: 128 MB -> ~40 MB.

#define NROWS  16384
#define DDIM   2048
#define NCLS   1000
#define NBIN   1024
#define BLK    256
#define CHUNK  4
#define NWAVES (NROWS / CHUNK)            // 4096
#define MGRID  (NWAVES / (BLK / 64))      // 1024

// ---- ws layout (ints/floats, 4 B) ----
// cnt[NBIN] | cur[NBIN] | sorted[NROWS] | wavesum[NWAVES]
#define WS_CNT    0
#define WS_CUR    (NBIN)
#define WS_SORTED (2 * NBIN)
#define WS_WSUM   (2 * NBIN + NROWS)
#define WS_NEEDED ((size_t)(2 * NBIN + NROWS + NWAVES) * 4)

__global__ void dnl_zero_kernel(int* __restrict__ cnt) {
    const int i = blockIdx.x * blockDim.x + threadIdx.x;
    if (i < NBIN) cnt[i] = 0;
}

__global__ void dnl_histo_kernel(const int* __restrict__ labels,
                                 int* __restrict__ cnt) {
    const int i = blockIdx.x * blockDim.x + threadIdx.x;
    if (i < NROWS) atomicAdd(&cnt[labels[i]], 1);
}

// 1 block, NBIN threads: exclusive scan cnt -> cur (scatter cursors)
__global__ __launch_bounds__(NBIN) void dnl_scan_kernel(
    const int* __restrict__ cnt, int* __restrict__ cur) {
    __shared__ int a[NBIN], b[NBIN];
    const int tid = threadIdx.x;
    a[tid] = cnt[tid];
    __syncthreads();
    int* src = a; int* dst = b;
    for (int d = 1; d < NBIN; d <<= 1) {
        dst[tid] = (tid >= d) ? src[tid] + src[tid - d] : src[tid];
        __syncthreads();
        int* tmp = src; src = dst; dst = tmp;
    }
    cur[tid] = src[tid] - cnt[tid];   // exclusive
}

__global__ void dnl_scatter_kernel(const int* __restrict__ labels,
                                   int* __restrict__ cur,
                                   int* __restrict__ sorted) {
    const int i = blockIdx.x * blockDim.x + threadIdx.x;
    if (i < NROWS) {
        const int p = atomicAdd(&cur[labels[i]], 1);
        sorted[p] = i;
    }
}

__global__ __launch_bounds__(BLK) void dnl_main_sorted(
    const float* __restrict__ s_emb,
    const float* __restrict__ t_emb,
    const float* __restrict__ T_EMB,
    const int*   __restrict__ labels,
    const int*   __restrict__ sorted,
    float*       __restrict__ wavesum)   // [NWAVES]
{
    const int tid  = threadIdx.x;
    const int lane = tid & 63;
    const int w    = blockIdx.x * (BLK / 64) + (tid >> 6);

    float4 cv[8];                 // class center: 32 floats/lane in regs
    float  ccs = 0.f;             // ||c||^2 (full-row, all lanes)
    int    cur_class = -1;
    float  acc = 0.f;

    for (int r = 0; r < CHUNK; ++r) {
        const int row   = sorted[w * CHUNK + r];
        const int label = labels[row];

        if (label != cur_class) {           // wave-uniform branch
            cur_class = label;
            const float4* c4 = (const float4*)(T_EMB + (size_t)label * DDIM);
            float cc = 0.f;
            #pragma unroll
            for (int j = 0; j < 8; ++j) cv[j] = c4[lane + j * 64];
            #pragma unroll
            for (int j = 0; j < 8; ++j) {
                const float4 c = cv[j];
                cc += c.x*c.x + c.y*c.y + c.z*c.z + c.w*c.w;
            }
            #pragma unroll
            for (int off = 32; off > 0; off >>= 1)
                cc += __shfl_xor(cc, off, 64);
            ccs = cc;
        }

        const float4* s4 = (const float4*)(s_emb + (size_t)row * DDIM);
        const float4* t4 = (const float4*)(t_emb + (size_t)row * DDIM);
        float ss = 0.f, tt = 0.f, sc = 0.f;
        #pragma unroll
        for (int j = 0; j < 8; ++j) {
            const float4 s = s4[lane + j * 64];
            const float4 t = t4[lane + j * 64];
            const float4 c = cv[j];
            ss += s.x*s.x + s.y*s.y + s.z*s.z + s.w*s.w;
            tt += t.x*t.x + t.y*t.y + t.z*t.z + t.w*t.w;
            sc += s.x*c.x + s.y*c.y + s.z*c.z + s.w*c.w;
        }
        #pragma unroll
        for (int off = 32; off > 0; off >>= 1) {
            ss += __shfl_xor(ss, off, 64);
            tt += __shfl_xor(tt, off, 64);
            sc += __shfl_xor(sc, off, 64);
        }

        const float max_norm = fmaxf(sqrtf(ss), sqrtf(tt));
        acc += 1.0f - sc / (sqrtf(ccs) * max_norm);
    }

    if (lane == 0) wavesum[w] = acc;
}

__global__ __launch_bounds__(BLK) void dnl_reduce_kernel(
    const float* __restrict__ wavesum,
    float*       __restrict__ out)
{
    const int tid = threadIdx.x;
    const float4* w4 = (const float4*)wavesum;
    float sum = 0.f;
    #pragma unroll
    for (int j = 0; j < NWAVES / 4 / BLK; ++j) {   // 4 iters
        const float4 v = w4[tid + j * BLK];
        sum += v.x + v.y + v.z + v.w;
    }
    #pragma unroll
    for (int off = 32; off > 0; off >>= 1)
        sum += __shfl_xor(sum, off, 64);
    __shared__ float red[4];
    if ((tid & 63) == 0) red[tid >> 6] = sum;
    __syncthreads();
    if (tid == 0)
        out[0] = (red[0] + red[1] + red[2] + red[3]) * (1.0f / (float)NROWS);
}

// ---- fallback (ws too small): R2-style wave-per-row, atomic out ----
__global__ __launch_bounds__(BLK) void dnl_main_atomic_kernel(
    const float* __restrict__ s_emb,
    const float* __restrict__ t_emb,
    const float* __restrict__ T_EMB,
    const int*   __restrict__ labels,
    float*       __restrict__ out)
{
    const int tid  = threadIdx.x;
    const int lane = tid & 63;
    const int row  = blockIdx.x * (BLK / 64) + (tid >> 6);
    const int label = labels[row];

    const float4* s4 = (const float4*)(s_emb + (size_t)row   * DDIM);
    const float4* t4 = (const float4*)(t_emb + (size_t)row   * DDIM);
    const float4* c4 = (const float4*)(T_EMB + (size_t)label * DDIM);

    float ss = 0.f, tt = 0.f, sc = 0.f, cc = 0.f;
    #pragma unroll
    for (int j = 0; j < 8; ++j) {
        const int k = lane + j * 64;
        const float4 s = s4[k];
        const float4 t = t4[k];
        const float4 c = c4[k];
        ss += s.x*s.x + s.y*s.y + s.z*s.z + s.w*s.w;
        tt += t.x*t.x + t.y*t.y + t.z*t.z + t.w*t.w;
        sc += s.x*c.x + s.y*c.y + s.z*c.z + s.w*c.w;
        cc += c.x*c.x + c.y*c.y + c.z*c.z + c.w*c.w;
    }
    #pragma unroll
    for (int off = 32; off > 0; off >>= 1) {
        ss += __shfl_xor(ss, off, 64);
        tt += __shfl_xor(tt, off, 64);
        sc += __shfl_xor(sc, off, 64);
        cc += __shfl_xor(cc, off, 64);
    }
    if (lane == 0) {
        const float max_norm = fmaxf(sqrtf(ss), sqrtf(tt));
        atomicAdd(out, (1.0f - sc / (sqrtf(cc) * max_norm)) * (1.0f / (float)NROWS));
    }
}

extern "C" void kernel_launch(void* const* d_in, const int* in_sizes, int n_in,
                              void* d_out, int out_size, void* d_ws, size_t ws_size,
                              hipStream_t stream) {
    const float* s_emb  = (const float*)d_in[0];
    const float* t_emb  = (const float*)d_in[1];
    const float* T_EMB  = (const float*)d_in[2];
    const int*   labels = (const int*)d_in[3];
    float* out = (float*)d_out;

    if (ws_size >= WS_NEEDED) {
        int*   cnt     = (int*)d_ws + WS_CNT;
        int*   cur     = (int*)d_ws + WS_CUR;
        int*   sorted  = (int*)d_ws + WS_SORTED;
        float* wavesum = (float*)d_ws + WS_WSUM;

        dnl_zero_kernel   <<<(NBIN + 255) / 256, 256, 0, stream>>>(cnt);
        dnl_histo_kernel  <<<NROWS / 256, 256, 0, stream>>>(labels, cnt);
        dnl_scan_kernel   <<<1, NBIN, 0, stream>>>(cnt, cur);
        dnl_scatter_kernel<<<NROWS / 256, 256, 0, stream>>>(labels, cur, sorted);
        dnl_main_sorted   <<<MGRID, BLK, 0, stream>>>(s_emb, t_emb, T_EMB,
                                                      labels, sorted, wavesum);
        dnl_reduce_kernel <<<1, BLK, 0, stream>>>(wavesum, out);
    } else {
        hipMemsetAsync(d_out, 0, sizeof(float), stream);
        dnl_main_atomic_kernel<<<NROWS / (BLK / 64), BLK, 0, stream>>>(
            s_emb, t_emb, T_EMB, labels, out);
    }
}

// Round 5
// 266.185 us; speedup vs baseline: 1.1588x; 1.1588x over previous
//
#include <hip/hip_runtime.h>

// DirectNormLoss: B=16384 rows, D=2048 features, 1000 classes.
// loss = mean_i [ 1 - <s_i, c_i> / (||c_i|| * max(||s_i||, ||t_i||)) ]
//
// R4: R3 falsified "logical traffic is the wall" (142MB vs 187MB fetch,
// same 110us). Working set (264MB) ~= LLC (256MB); s/t/c streams contend on
// the L1->L2->LLC path. This round: R2 structure (wave/row, natural order,
// 16384 waves) + NONTEMPORAL loads for s/t (no LLC allocation) so LLC serves
// only the center re-reads (the only reused data). Sort chain dropped.

#define NROWS  16384
#define DDIM   2048
#define BLK    256
#define WPB    (BLK / 64)          // 4 waves per block
#define GRID   (NROWS / WPB)       // 4096 blocks -> 16384 waves, 1 row each

typedef float v4f __attribute__((ext_vector_type(4)));

__global__ __launch_bounds__(BLK, 2) void dnl_main_kernel(
    const float* __restrict__ s_emb,
    const float* __restrict__ t_emb,
    const float* __restrict__ T_EMB,
    const int*   __restrict__ labels,
    float*       __restrict__ partial)   // [NROWS]
{
    const int tid  = threadIdx.x;
    const int lane = tid & 63;
    const int row  = blockIdx.x * WPB + (tid >> 6);   // wave-uniform

    const int label = labels[row];                    // issued first (scalar)

    const v4f* s4 = (const v4f*)(s_emb + (size_t)row   * DDIM);
    const v4f* t4 = (const v4f*)(t_emb + (size_t)row   * DDIM);
    const v4f* c4 = (const v4f*)(T_EMB + (size_t)label * DDIM);

    float ss = 0.f, tt = 0.f, sc = 0.f, cc = 0.f;
    // 512 float4 per row; 64 lanes -> 8 per lane per stream.
    // s/t: nontemporal (streamed once, keep out of LLC); c: cached (reused).
    #pragma unroll
    for (int j = 0; j < 8; ++j) {
        const int k = lane + j * 64;
        const v4f s = __builtin_nontemporal_load(&s4[k]);
        const v4f t = __builtin_nontemporal_load(&t4[k]);
        const v4f c = c4[k];
        ss += s.x*s.x + s.y*s.y + s.z*s.z + s.w*s.w;
        tt += t.x*t.x + t.y*t.y + t.z*t.z + t.w*t.w;
        sc += s.x*c.x + s.y*c.y + s.z*c.z + s.w*c.w;
        cc += c.x*c.x + c.y*c.y + c.z*c.z + c.w*c.w;
    }

    // wave-64 xor butterfly: all lanes end with full row sums
    #pragma unroll
    for (int off = 32; off > 0; off >>= 1) {
        ss += __shfl_xor(ss, off, 64);
        tt += __shfl_xor(tt, off, 64);
        sc += __shfl_xor(sc, off, 64);
        cc += __shfl_xor(cc, off, 64);
    }

    if (lane == 0) {
        const float max_norm = fmaxf(sqrtf(ss), sqrtf(tt));
        partial[row] = 1.0f - sc / (sqrtf(cc) * max_norm);
    }
}

__global__ __launch_bounds__(BLK) void dnl_reduce_kernel(
    const float* __restrict__ partial,
    float*       __restrict__ out)
{
    const int tid = threadIdx.x;
    const float4* p4 = (const float4*)partial;
    // NROWS/4 = 4096 float4; 256 threads -> 16 each, coalesced.
    float sum = 0.f;
    #pragma unroll
    for (int j = 0; j < 16; ++j) {
        const float4 v = p4[tid + j * BLK];
        sum += v.x + v.y + v.z + v.w;
    }

    #pragma unroll
    for (int off = 32; off > 0; off >>= 1)
        sum += __shfl_xor(sum, off, 64);

    __shared__ float red[4];
    if ((tid & 63) == 0) red[tid >> 6] = sum;
    __syncthreads();
    if (tid == 0)
        out[0] = (red[0] + red[1] + red[2] + red[3]) * (1.0f / (float)NROWS);
}

// Atomic fallback (only if ws too small).
__global__ __launch_bounds__(BLK, 2) void dnl_main_atomic_kernel(
    const float* __restrict__ s_emb,
    const float* __restrict__ t_emb,
    const float* __restrict__ T_EMB,
    const int*   __restrict__ labels,
    float*       __restrict__ out)
{
    const int tid  = threadIdx.x;
    const int lane = tid & 63;
    const int row  = blockIdx.x * WPB + (tid >> 6);
    const int label = labels[row];

    const v4f* s4 = (const v4f*)(s_emb + (size_t)row   * DDIM);
    const v4f* t4 = (const v4f*)(t_emb + (size_t)row   * DDIM);
    const v4f* c4 = (const v4f*)(T_EMB + (size_t)label * DDIM);

    float ss = 0.f, tt = 0.f, sc = 0.f, cc = 0.f;
    #pragma unroll
    for (int j = 0; j < 8; ++j) {
        const int k = lane + j * 64;
        const v4f s = __builtin_nontemporal_load(&s4[k]);
        const v4f t = __builtin_nontemporal_load(&t4[k]);
        const v4f c = c4[k];
        ss += s.x*s.x + s.y*s.y + s.z*s.z + s.w*s.w;
        tt += t.x*t.x + t.y*t.y + t.z*t.z + t.w*t.w;
        sc += s.x*c.x + s.y*c.y + s.z*c.z + s.w*c.w;
        cc += c.x*c.x + c.y*c.y + c.z*c.z + c.w*c.w;
    }
    #pragma unroll
    for (int off = 32; off > 0; off >>= 1) {
        ss += __shfl_xor(ss, off, 64);
        tt += __shfl_xor(tt, off, 64);
        sc += __shfl_xor(sc, off, 64);
        cc += __shfl_xor(cc, off, 64);
    }
    if (lane == 0) {
        const float max_norm = fmaxf(sqrtf(ss), sqrtf(tt));
        atomicAdd(out, (1.0f - sc / (sqrtf(cc) * max_norm)) * (1.0f / (float)NROWS));
    }
}

extern "C" void kernel_launch(void* const* d_in, const int* in_sizes, int n_in,
                              void* d_out, int out_size, void* d_ws, size_t ws_size,
                              hipStream_t stream) {
    const float* s_emb  = (const float*)d_in[0];
    const float* t_emb  = (const float*)d_in[1];
    const float* T_EMB  = (const float*)d_in[2];
    const int*   labels = (const int*)d_in[3];
    float* out = (float*)d_out;

    if (ws_size >= (size_t)NROWS * sizeof(float)) {
        float* partial = (float*)d_ws;
        dnl_main_kernel<<<GRID, BLK, 0, stream>>>(s_emb, t_emb, T_EMB, labels, partial);
        dnl_reduce_kernel<<<1, BLK, 0, stream>>>(partial, out);
    } else {
        hipMemsetAsync(d_out, 0, sizeof(float), stream);
        dnl_main_atomic_kernel<<<GRID, BLK, 0, stream>>>(s_emb, t_emb, T_EMB, labels, out);
    }
}